// Round 1
// baseline (772.107 us; speedup 1.0000x reference)
//
#include <hip/hip_runtime.h>

#define NN 100000
#define EE 1000000
#define FF 128
#define HH 64
#define GG 128

// ---------- degree ----------
__global__ void k_init_deg(float* deg) {
    int i = blockIdx.x * 256 + threadIdx.x;
    if (i < NN) deg[i] = 1.0f;
}
__global__ void k_deg_edges(const int* __restrict__ ei, float* deg) {
    int e = blockIdx.x * 256 + threadIdx.x;
    if (e < EE) unsafeAtomicAdd(&deg[ei[EE + e]], 1.0f);
}
__global__ void k_rsqrt(float* deg) {
    int i = blockIdx.x * 256 + threadIdx.x;
    if (i < NN) deg[i] = rsqrtf(deg[i]);
}

// ---------- dense: Y[N,64] = X[N,K] @ W[K,64] ----------
// One thread per output element; wave's 64 lanes share one X row
// (wave-uniform loads), W staged in LDS (2-way bank alias = free).
template<int K>
__global__ void k_matmul(const float* __restrict__ X, const float* __restrict__ W,
                         float* __restrict__ Y) {
    __shared__ float Wl[K * HH];
    for (int i = threadIdx.x; i < K * HH; i += 256) Wl[i] = W[i];
    __syncthreads();
    const int col  = threadIdx.x & 63;
    const int rsub = threadIdx.x >> 6;            // 0..3
    const int rowBase = blockIdx.x * 32;          // 32 rows per block
    for (int rr = rsub; rr < 32; rr += 4) {
        const int r = rowBase + rr;
        if (r >= NN) continue;
        const float4* xr = (const float4*)(X + (size_t)r * K);
        float acc = 0.0f;
#pragma unroll
        for (int k4 = 0; k4 < K / 4; ++k4) {
            float4 xv = xr[k4];
            acc = fmaf(xv.x, Wl[(k4 * 4 + 0) * HH + col], acc);
            acc = fmaf(xv.y, Wl[(k4 * 4 + 1) * HH + col], acc);
            acc = fmaf(xv.z, Wl[(k4 * 4 + 2) * HH + col], acc);
            acc = fmaf(xv.w, Wl[(k4 * 4 + 3) * HH + col], acc);
        }
        Y[(size_t)r * HH + col] = acc;
    }
}

// ---------- edge scatter: Acc[dst,:] += Hm[src,:] * dis[src]*dis[dst] ----------
// One wave per edge (64 lanes = 64 cols): src/dst/norm wave-uniform,
// gather + atomic both coalesced.
__global__ void k_scatter(const int* __restrict__ ei, const float* __restrict__ dis,
                          const float* __restrict__ Hm, float* __restrict__ Acc) {
    const long long idx = (long long)blockIdx.x * 256 + threadIdx.x;
    const int e   = (int)(idx >> 6);
    const int col = (int)(idx & 63);
    const int s = ei[e];
    const int d = ei[EE + e];
    const float norm = dis[s] * dis[d];
    const float v = Hm[(size_t)s * HH + col] * norm;
    unsafeAtomicAdd(&Acc[(size_t)d * HH + col], v);
}

// ---------- combine: A = relu(A + B*dis^2 + b) ----------
__global__ void k_combine(float* __restrict__ A, const float* __restrict__ B,
                          const float* __restrict__ dis, const float* __restrict__ b) {
    const long long idx = (long long)blockIdx.x * 256 + threadIdx.x;
    const int n   = (int)(idx >> 6);
    const int col = (int)(idx & 63);
    const float di = dis[n];
    float v = A[idx] + B[idx] * di * di + b[col];
    A[idx] = v > 0.0f ? v : 0.0f;
}

// ---------- pool: g[batch[n],:] += A[n,:] ----------
__global__ void k_pool(const int* __restrict__ batch, const float* __restrict__ A,
                       float* __restrict__ g) {
    const long long idx = (long long)blockIdx.x * 256 + threadIdx.x;
    const int n   = (int)(idx >> 6);
    const int col = (int)(idx & 63);
    unsafeAtomicAdd(&g[(size_t)batch[n] * HH + col], A[idx]);
}

// ---------- head dense 1: g2 = relu(g @ Wl1 + bl1), [128,64]@[64,64] ----------
__global__ void k_head1(const float* __restrict__ g, const float* __restrict__ W,
                        const float* __restrict__ b, float* __restrict__ g2) {
    const int idx = blockIdx.x * 256 + threadIdx.x;   // 8192 outputs
    const int row = idx >> 6;
    const int col = idx & 63;
    const float* gr = g + (size_t)row * HH;
    float acc = b[col];
#pragma unroll
    for (int k = 0; k < HH; ++k) acc = fmaf(gr[k], W[k * HH + col], acc);
    g2[idx] = acc > 0.0f ? acc : 0.0f;
}

// ---------- head dense 2: out[r] = g2[r,:] . Wl2 + bl2 ----------
__global__ void k_head2(const float* __restrict__ g2, const float* __restrict__ W,
                        const float* __restrict__ b, float* __restrict__ out) {
    const int r = threadIdx.x;   // 128 threads
    if (r >= GG) return;
    const float* gr = g2 + (size_t)r * HH;
    float acc = 0.0f;
#pragma unroll
    for (int k = 0; k < HH; ++k) acc = fmaf(gr[k], W[k], acc);
    out[r] = acc + b[0];
}

extern "C" void kernel_launch(void* const* d_in, const int* in_sizes, int n_in,
                              void* d_out, int out_size, void* d_ws, size_t ws_size,
                              hipStream_t stream) {
    const float* x   = (const float*)d_in[0];
    const int*   ei  = (const int*)d_in[1];
    const int*   bat = (const int*)d_in[2];
    const float* W1  = (const float*)d_in[3];
    const float* b1  = (const float*)d_in[4];
    const float* W2  = (const float*)d_in[5];
    const float* b2  = (const float*)d_in[6];
    const float* Wl1 = (const float*)d_in[7];
    const float* bl1 = (const float*)d_in[8];
    const float* Wl2 = (const float*)d_in[9];
    const float* bl2 = (const float*)d_in[10];
    float* out = (float*)d_out;

    char* w = (char*)d_ws;
    float* dis = (float*)(w);                           // N floats
    float* A   = (float*)(w + 400128);                  // N*64 floats
    float* B   = (float*)(w + 400128 + 25600000);       // N*64 floats
    float* g   = (float*)(w + 400128 + 2 * 25600000ll); // 128*64
    float* g2  = g + GG * HH;

    // degree / normalization
    k_init_deg<<<(NN + 255) / 256, 256, 0, stream>>>(dis);
    k_deg_edges<<<(EE + 255) / 256, 256, 0, stream>>>(ei, dis);
    k_rsqrt<<<(NN + 255) / 256, 256, 0, stream>>>(dis);

    // conv1: B = x @ W1
    k_matmul<FF><<<NN / 32, 256, 0, stream>>>(x, W1, B);
    hipMemsetAsync(A, 0, (size_t)NN * HH * sizeof(float), stream);
    k_scatter<<<(EE * HH) / 256, 256, 0, stream>>>(ei, dis, B, A);
    k_combine<<<(NN * HH) / 256, 256, 0, stream>>>(A, B, dis, b1);

    // conv2: B = A @ W2
    k_matmul<HH><<<NN / 32, 256, 0, stream>>>(A, W2, B);
    hipMemsetAsync(A, 0, (size_t)NN * HH * sizeof(float), stream);
    k_scatter<<<(EE * HH) / 256, 256, 0, stream>>>(ei, dis, B, A);
    k_combine<<<(NN * HH) / 256, 256, 0, stream>>>(A, B, dis, b2);

    // pool + head
    hipMemsetAsync(g, 0, (size_t)GG * HH * sizeof(float), stream);
    k_pool<<<(NN * HH) / 256, 256, 0, stream>>>(bat, A, g);
    k_head1<<<(GG * HH) / 256, 256, 0, stream>>>(g, Wl1, bl1, g2);
    k_head2<<<1, 128, 0, stream>>>(g2, Wl2, bl2, out);
}

// Round 2
// 495.627 us; speedup vs baseline: 1.5578x; 1.5578x over previous
//
#include <hip/hip_runtime.h>

#define NN 100000
#define EE 1000000
#define FF 128
#define HH 64
#define GG 128
#define NB 391   // scan blocks: 391*256 = 100096 >= NN

// ---------- CSR build ----------
__global__ void k_hist(const int* __restrict__ ei, int* __restrict__ cnt) {
    int e = blockIdx.x * 256 + threadIdx.x;
    if (e < EE) atomicAdd(&cnt[ei[EE + e]], 1);
}

__global__ void k_scan1(const int* __restrict__ cnt, int* __restrict__ part) {
    int i = blockIdx.x * 256 + threadIdx.x;
    int v = (i < NN) ? cnt[i] : 0;
    for (int o = 1; o < 64; o <<= 1) v += __shfl_xor(v, o);
    __shared__ int ws[4];
    if ((threadIdx.x & 63) == 0) ws[threadIdx.x >> 6] = v;
    __syncthreads();
    if (threadIdx.x == 0) part[blockIdx.x] = ws[0] + ws[1] + ws[2] + ws[3];
}

__global__ void k_scan2(int* __restrict__ part) {   // exclusive scan, 1 block
    __shared__ int buf[512];
    int t = threadIdx.x;
    int v = (t < NB) ? part[t] : 0;
    buf[t] = v; __syncthreads();
    for (int o = 1; o < 512; o <<= 1) {
        int u = (t >= o) ? buf[t - o] : 0;
        __syncthreads();
        buf[t] += u;
        __syncthreads();
    }
    if (t < NB) part[t] = buf[t] - v;
}

__global__ void k_scan3(const int* __restrict__ cnt, const int* __restrict__ part,
                        int* __restrict__ row_ptr, int* __restrict__ cursor,
                        float* __restrict__ dis) {
    int i = blockIdx.x * 256 + threadIdx.x;
    int v = (i < NN) ? cnt[i] : 0;
    int lane = threadIdx.x & 63, w = threadIdx.x >> 6;
    int incl = v;
    for (int o = 1; o < 64; o <<= 1) { int u = __shfl_up(incl, o); if (lane >= o) incl += u; }
    __shared__ int ws[4];
    if (lane == 63) ws[w] = incl;
    __syncthreads();
    int woff = 0;
    for (int k = 0; k < w; ++k) woff += ws[k];
    int excl = incl - v + woff + part[blockIdx.x];
    if (i < NN) {
        row_ptr[i] = excl;
        cursor[i]  = excl;
        dis[i] = rsqrtf((float)(v + 1));
    }
    if (i == 0) row_ptr[NN] = EE;
}

__global__ void k_place(const int* __restrict__ ei, int* __restrict__ cursor,
                        int* __restrict__ srcs) {
    int e = blockIdx.x * 256 + threadIdx.x;
    if (e < EE) {
        int d = ei[EE + e];
        int p = atomicAdd(&cursor[d], 1);
        srcs[p] = ei[e];
    }
}

// ---------- dense: Y[N,64] = (X[N,K] @ W[K,64]) * dis[row] ----------
template<int K>
__global__ void k_matmul_s(const float* __restrict__ X, const float* __restrict__ W,
                           const float* __restrict__ dis, float* __restrict__ Y) {
    __shared__ float Wl[K * HH];
    for (int i = threadIdx.x; i < K * HH; i += 256) Wl[i] = W[i];
    __syncthreads();
    const int col  = threadIdx.x & 63;
    const int rsub = threadIdx.x >> 6;
    const int rowBase = blockIdx.x * 32;
    for (int rr = rsub; rr < 32; rr += 4) {
        const int r = rowBase + rr;
        if (r >= NN) continue;
        const float4* xr = (const float4*)(X + (size_t)r * K);
        float acc = 0.0f;
#pragma unroll
        for (int k4 = 0; k4 < K / 4; ++k4) {
            float4 xv = xr[k4];
            acc = fmaf(xv.x, Wl[(k4 * 4 + 0) * HH + col], acc);
            acc = fmaf(xv.y, Wl[(k4 * 4 + 1) * HH + col], acc);
            acc = fmaf(xv.z, Wl[(k4 * 4 + 2) * HH + col], acc);
            acc = fmaf(xv.w, Wl[(k4 * 4 + 3) * HH + col], acc);
        }
        Y[(size_t)r * HH + col] = acc * dis[r];
    }
}

// ---------- gather conv: out[d] = relu(dd*(sum Hs[src] + Hs[d]) + b) ----------
// Hs rows already scaled by dis[src]. One wave per node; optional fused pool.
template<bool POOL>
__global__ void k_gconv(const int* __restrict__ row_ptr, const int* __restrict__ srcs,
                        const float* __restrict__ dis, const float* __restrict__ Hs,
                        const float* __restrict__ b, float* __restrict__ Out,
                        const int* __restrict__ batch, float* __restrict__ g) {
    const int node = blockIdx.x * 4 + (threadIdx.x >> 6);
    if (node >= NN) return;
    const int lane = threadIdx.x & 63;
    const int p1 = row_ptr[node + 1];
    int p = row_ptr[node];
    float acc = 0.0f;
    int s_next = (p < p1) ? srcs[p] : 0;
    while (p < p1) {
        int s = s_next;
        ++p;
        if (p < p1) s_next = srcs[p];       // prefetch next src index
        acc += Hs[(size_t)s * HH + lane];
    }
    const float dd = dis[node];
    float v = (acc + Hs[(size_t)node * HH + lane]) * dd + b[lane];
    v = fmaxf(v, 0.0f);
    if (POOL) {
        unsafeAtomicAdd(&g[(size_t)batch[node] * HH + lane], v);
    } else {
        Out[(size_t)node * HH + lane] = v;
    }
}

// ---------- head ----------
__global__ void k_head1(const float* __restrict__ g, const float* __restrict__ W,
                        const float* __restrict__ b, float* __restrict__ g2) {
    const int idx = blockIdx.x * 256 + threadIdx.x;
    const int row = idx >> 6;
    const int col = idx & 63;
    const float* gr = g + (size_t)row * HH;
    float acc = b[col];
#pragma unroll
    for (int k = 0; k < HH; ++k) acc = fmaf(gr[k], W[k * HH + col], acc);
    g2[idx] = acc > 0.0f ? acc : 0.0f;
}

__global__ void k_head2(const float* __restrict__ g2, const float* __restrict__ W,
                        const float* __restrict__ b, float* __restrict__ out) {
    const int r = threadIdx.x;
    if (r >= GG) return;
    const float* gr = g2 + (size_t)r * HH;
    float acc = 0.0f;
#pragma unroll
    for (int k = 0; k < HH; ++k) acc = fmaf(gr[k], W[k], acc);
    out[r] = acc + b[0];
}

extern "C" void kernel_launch(void* const* d_in, const int* in_sizes, int n_in,
                              void* d_out, int out_size, void* d_ws, size_t ws_size,
                              hipStream_t stream) {
    const float* x   = (const float*)d_in[0];
    const int*   ei  = (const int*)d_in[1];
    const int*   bat = (const int*)d_in[2];
    const float* W1  = (const float*)d_in[3];
    const float* b1  = (const float*)d_in[4];
    const float* W2  = (const float*)d_in[5];
    const float* b2  = (const float*)d_in[6];
    const float* Wl1 = (const float*)d_in[7];
    const float* bl1 = (const float*)d_in[8];
    const float* Wl2 = (const float*)d_in[9];
    const float* bl2 = (const float*)d_in[10];
    float* out = (float*)d_out;

    char* w = (char*)d_ws;
    float* dis     = (float*)(w);                    // 400128 B
    int*   cnt     = (int*)  (w + 400128);           // 400128 B
    int*   row_ptr = (int*)  (w + 800256);           // 400384 B (N+1)
    int*   cursor  = (int*)  (w + 1200640);          // 400128 B
    int*   part    = (int*)  (w + 1600768);          // 2048 B
    int*   srcs    = (int*)  (w + 1602816);          // 4000000 B
    float* B       = (float*)(w + 5602816);          // 25.6 MB
    float* A       = (float*)(w + 31202816);         // 25.6 MB
    float* g       = (float*)(w + 56802816);         // 32 KB
    float* g2      = g + GG * HH;

    // ---- CSR build (once; reused by both convs) ----
    hipMemsetAsync(cnt, 0, (size_t)NN * sizeof(int), stream);
    k_hist <<<(EE + 255) / 256, 256, 0, stream>>>(ei, cnt);
    k_scan1<<<NB, 256, 0, stream>>>(cnt, part);
    k_scan2<<<1, 512, 0, stream>>>(part);
    k_scan3<<<NB, 256, 0, stream>>>(cnt, part, row_ptr, cursor, dis);
    k_place<<<(EE + 255) / 256, 256, 0, stream>>>(ei, cursor, srcs);

    // ---- conv1 ----
    k_matmul_s<FF><<<(NN + 31) / 32, 256, 0, stream>>>(x, W1, dis, B);
    k_gconv<false><<<(NN + 3) / 4, 256, 0, stream>>>(row_ptr, srcs, dis, B, b1, A, nullptr, nullptr);

    // ---- conv2 (pool fused) ----
    k_matmul_s<HH><<<(NN + 31) / 32, 256, 0, stream>>>(A, W2, dis, B);
    hipMemsetAsync(g, 0, (size_t)GG * HH * sizeof(float), stream);
    k_gconv<true><<<(NN + 3) / 4, 256, 0, stream>>>(row_ptr, srcs, dis, B, b2, nullptr, bat, g);

    // ---- head ----
    k_head1<<<(GG * HH) / 256, 256, 0, stream>>>(g, Wl1, bl1, g2);
    k_head2<<<1, 128, 0, stream>>>(g2, Wl2, bl2, out);
}